// Round 15
// baseline (233.416 us; speedup 1.0000x reference)
//
#include <hip/hip_runtime.h>
#include <stdint.h>
#include <math.h>

#define EMB 2048
#define NHq 16
#define NGk 4
#define HD 128
#define Bb 2
#define Tt 2048
#define MROWS (Bb*Tt)      // 4096
#define QKVN 3072          // 2048 q + 512 k + 512 v
#define NQT 32             // q-tiles of 64 rows per (b,h)

typedef __bf16 bf16x8 __attribute__((ext_vector_type(8)));
typedef float f32x4 __attribute__((ext_vector_type(4)));
typedef unsigned int u32x4 __attribute__((ext_vector_type(4)));
typedef unsigned short u16;
typedef unsigned int u32;

__device__ __forceinline__ u16 f2bf(float f) {
    unsigned int u = __float_as_uint(f);
    u += 0x7fff + ((u >> 16) & 1);          // round-to-nearest-even
    return (u16)(u >> 16);
}
__device__ __forceinline__ float bf2f(u16 u) {
    return __uint_as_float(((u32)u) << 16);
}
__device__ __forceinline__ u32 cvt_pk_bf16(float lo, float hi) {
    u32 r;
    asm("v_cvt_pk_bf16_f32 %0, %1, %2" : "=v"(r) : "v"(lo), "v"(hi));
    return r;
}

#define GLOAD_LDS16(g, l) \
    __builtin_amdgcn_global_load_lds((const __attribute__((address_space(1))) void*)(g), \
                                     (__attribute__((address_space(3))) void*)(l), 16, 0, 0)
#define FENCE asm volatile("" ::: "memory")
#define BARRIER { FENCE; __builtin_amdgcn_s_barrier(); FENCE; }
#define VMCNT(n) asm volatile("s_waitcnt vmcnt(" #n ")")

// ---------------- cast f32 -> bf16, vectorized ----------------
__global__ void cast_bf16_kernel(const float* __restrict__ src, u16* __restrict__ dst, int n4) {
    int i = blockIdx.x * blockDim.x + threadIdx.x;
    if (i < n4) {
        float4 v = reinterpret_cast<const float4*>(src)[i];
        ushort4 o;
        o.x = f2bf(v.x); o.y = f2bf(v.y); o.z = f2bf(v.z); o.w = f2bf(v.w);
        reinterpret_cast<ushort4*>(dst)[i] = o;
    }
}

// ---------------- fused weight cast: Wq|Wk|Wv|Wo -> contiguous bf16 ----------------
__global__ void wcast_kernel(const float* __restrict__ Wq, const float* __restrict__ Wk,
                             const float* __restrict__ Wv, const float* __restrict__ Wo,
                             u16* __restrict__ dst) {
    int i = blockIdx.x * blockDim.x + threadIdx.x;     // float4 chunk index, 2621440 total
    const float* src; int local;
    if (i < 1048576)      { src = Wq; local = i; }
    else if (i < 1310720) { src = Wk; local = i - 1048576; }
    else if (i < 1572864) { src = Wv; local = i - 1310720; }
    else                  { src = Wo; local = i - 1572864; }
    float4 v = reinterpret_cast<const float4*>(src)[local];
    ushort4 o;
    o.x = f2bf(v.x); o.y = f2bf(v.y); o.z = f2bf(v.z); o.w = f2bf(v.w);
    reinterpret_cast<ushort4*>(dst)[i] = o;
}

// ---------------- RoPE cos/sin tables: [T][64] ----------------
__global__ void rope_tables_kernel(float* __restrict__ ctab, float* __restrict__ stab) {
    int t = blockIdx.x, i = threadIdx.x;     // grid T, block 64
    float inv = powf(10000.f, -2.f * (float)i / (float)HD);
    float ang = (float)t * inv;
    ctab[t * 64 + i] = cosf(ang);
    stab[t * 64 + i] = sinf(ang);
}

// ---------------- fused RoPE q+k: lin[M][3072] bf16 -> Qb / Kb bf16 ----------------
__global__ void rope_qk_kernel(const u16* __restrict__ lin, const float* __restrict__ ctab,
                               const float* __restrict__ stab, u16* __restrict__ Qb,
                               u16* __restrict__ Kb, float qscale) {
    // grid (T/4, NHq+NGk, B), block (64,4)
    int i = threadIdx.x;                       // pair index 0..63
    int tt = blockIdx.x * 4 + threadIdx.y;
    int hh = blockIdx.y, b = blockIdx.z;
    int coloff; u16* out; float scale;
    if (hh < NHq) { coloff = hh * HD; scale = qscale;
                    out = Qb + (((size_t)(b * NHq + hh)) * Tt + tt) * HD; }
    else { int g = hh - NHq; coloff = EMB + g * HD; scale = 1.f;
           out = Kb + (((size_t)(b * NGk + g)) * Tt + tt) * HD; }
    u32 pair = *reinterpret_cast<const u32*>(&lin[((size_t)(b * Tt + tt)) * QKVN + coloff + 2 * i]);
    float x1 = bf2f((u16)(pair & 0xffff)), x2 = bf2f((u16)(pair >> 16));
    float c = ctab[tt * 64 + i], s = stab[tt * 64 + i];
    ushort2 o;
    o.x = f2bf((x1 * c - x2 * s) * scale);
    o.y = f2bf((x1 * s + x2 * c) * scale);
    *reinterpret_cast<ushort2*>(&out[2 * i]) = o;
}

// ---------------- V relayout+transpose (bf16 copy): lin -> Vt[B][NG][HD][T], kv sigma-PERMUTED ----
__global__ void vtrans_kernel(const u16* __restrict__ lin, u16* __restrict__ vt) {
    // grid (T/64, NG, B), block (64,8)
    int tx = threadIdx.x, dy = threadIdx.y;
    int tt = blockIdx.x * 64 + tx;
    int g = blockIdx.y, b = blockIdx.z;
    int ttp = (tt & ~31) | (((tt >> 2) & 3) * 8 + ((tt >> 4) & 1) * 4 + (tt & 3));
    const u16* src = &lin[((size_t)(b * Tt + tt)) * QKVN + EMB + NGk * HD + g * HD];
    u16* dst = &vt[(((size_t)(b * NGk + g)) * HD) * Tt + ttp];
    #pragma unroll
    for (int k = 0; k < 16; ++k) {
        int d = dy + k * 8;
        dst[(size_t)d * Tt] = src[d];
    }
}

// ---------------- bf16 GEMM 128^2 (m97 structure): C = A @ W^T ----------------
template<int OUTBF>
__global__ __launch_bounds__(256) void gemm_bt(const u16* __restrict__ A, const u16* __restrict__ W,
                                               void* __restrict__ Cout, int M, int N, int K) {
    __shared__ u16 Atile[128 * 32];
    __shared__ u16 Btile[128 * 32];
    const int brow = blockIdx.x * 128;
    const int bcol = blockIdx.y * 128;
    const int t = threadIdx.x;
    const int w = t >> 6, l = t & 63;
    const int lr = l & 15, lq = l >> 4;
    const int wr = (w >> 1) * 64, wc = (w & 1) * 64;
    f32x4 acc[4][4] = {};
    const int nkt = K >> 5;
    for (int kt = 0; kt < nkt; ++kt) {
        const int k0 = kt * 32;
        #pragma unroll
        for (int i = 0; i < 2; ++i) {
            int f = i * 256 + t;
            int row = f >> 2, cb = (f & 3) * 8;
            GLOAD_LDS16(A + (size_t)(brow + row) * K + k0 + cb, &Atile[(i * 256 + w * 64) * 8]);
            GLOAD_LDS16(W + (size_t)(bcol + row) * K + k0 + cb, &Btile[(i * 256 + w * 64) * 8]);
        }
        __syncthreads();
        bf16x8 a[4], b[4];
        #pragma unroll
        for (int m = 0; m < 4; ++m)
            a[m] = *reinterpret_cast<const bf16x8*>(&Atile[(wr + m * 16 + lr) * 32 + lq * 8]);
        #pragma unroll
        for (int n = 0; n < 4; ++n)
            b[n] = *reinterpret_cast<const bf16x8*>(&Btile[(wc + n * 16 + lr) * 32 + lq * 8]);
        #pragma unroll
        for (int m = 0; m < 4; ++m)
            #pragma unroll
            for (int n = 0; n < 4; ++n)
                acc[m][n] = __builtin_amdgcn_mfma_f32_16x16x32_bf16(a[m], b[n], acc[m][n], 0, 0, 0);
        __syncthreads();
    }
    #pragma unroll
    for (int m = 0; m < 4; ++m)
        #pragma unroll
        for (int n = 0; n < 4; ++n)
            #pragma unroll
            for (int r = 0; r < 4; ++r) {
                size_t idx = (size_t)(brow + wr + m * 16 + lq * 4 + r) * N + bcol + wc + n * 16 + lr;
                if (OUTBF) ((u16*)Cout)[idx] = f2bf(acc[m][n][r]);
                else       ((float*)Cout)[idx] = acc[m][n][r];
            }
}

// ---------------- 256x256 4-phase GEMM v2: quadrant-aligned halftiles, reg-held B ----------------
template<int OUTBF>
__global__ __launch_bounds__(512) void gemm256(const u16* __restrict__ A, const u16* __restrict__ W,
                                               void* __restrict__ Cout, int M, int N, int K) {
    __shared__ __align__(16) char smem[131072];   // buf d: A 32KB @ d*65536, B 32KB @ +32768
    const int nbm = M >> 8;
    const int nwg = gridDim.x;
    const int cpx = nwg >> 3;
    const int swz = ((int)blockIdx.x & 7) * cpx + ((int)blockIdx.x >> 3);
    const int brow = (swz % nbm) << 8;
    const int bcol = (swz / nbm) << 8;
    const int t = threadIdx.x;
    const int l = t & 63, lr = l & 15, lq = l >> 4;
    const int w = t >> 6, wm = w >> 2, wn = w & 3;

    int lrj[2], slj[2], sej[2];
    #pragma unroll
    for (int j = 0; j < 2; ++j) {
        int c = j * 512 + t;
        lrj[j] = c >> 3; slj[j] = c & 7; sej[j] = (c & 7) ^ ((c >> 3) & 7);
    }

#define STGA(d, kt1, h) { \
    _Pragma("unroll") \
    for (int j = 0; j < 2; ++j) { \
        int row = (lrj[j] & 63) + (h) * 64 + (lrj[j] >> 6) * 128; \
        GLOAD_LDS16(A + (size_t)(brow + row) * K + (size_t)(kt1) * 64 + sej[j] * 8, \
                    smem + (d) * 65536 + row * 128 + slj[j] * 16); } }
#define STGB(d, kt1, h) { \
    _Pragma("unroll") \
    for (int j = 0; j < 2; ++j) { \
        int row = (lrj[j] & 31) + (h) * 32 + (lrj[j] >> 5) * 64; \
        GLOAD_LDS16(W + (size_t)(bcol + row) * K + (size_t)(kt1) * 64 + sej[j] * 8, \
                    smem + (d) * 65536 + 32768 + row * 128 + slj[j] * 16); } }
#define RDA(cur, mh) { \
    _Pragma("unroll") \
    for (int m = 0; m < 4; ++m) \
        _Pragma("unroll") \
        for (int kk = 0; kk < 2; ++kk) { \
            int row = wm * 128 + (mh) * 64 + m * 16 + lr; \
            int slr = (kk * 4 + lq) ^ (lr & 7); \
            af[m][kk] = *reinterpret_cast<const bf16x8*>(smem + (cur) * 65536 + row * 128 + slr * 16); } }
#define RDB(cur, nh, bq) { \
    _Pragma("unroll") \
    for (int n = 0; n < 2; ++n) \
        _Pragma("unroll") \
        for (int kk = 0; kk < 2; ++kk) { \
            int row = wn * 64 + (nh) * 32 + n * 16 + lr; \
            int slr = (kk * 4 + lq) ^ (lr & 7); \
            bq[n][kk] = *reinterpret_cast<const bf16x8*>(smem + (cur) * 65536 + 32768 + row * 128 + slr * 16); } }
#define MM(bq, mo, no) { \
    __builtin_amdgcn_s_setprio(1); \
    _Pragma("unroll") \
    for (int m = 0; m < 4; ++m) \
        _Pragma("unroll") \
        for (int n = 0; n < 2; ++n) \
            _Pragma("unroll") \
            for (int kk = 0; kk < 2; ++kk) \
                acc[(mo) + m][(no) + n] = __builtin_amdgcn_mfma_f32_16x16x32_bf16( \
                    af[m][kk], bq[n][kk], acc[(mo) + m][(no) + n], 0, 0, 0); \
    __builtin_amdgcn_s_setprio(0); }

    f32x4 acc[8][4] = {};
    bf16x8 af[4][2], b0[2][2], b1[2][2];
    const int nkt = K >> 6;

    STGA(0, 0, 0); STGB(0, 0, 0); STGB(0, 0, 1); STGA(0, 0, 1);
    VMCNT(4); BARRIER;

    for (int kt = 0; kt < nkt; ++kt) {
        const int cur = kt & 1, nxt = cur ^ 1;
        const bool more = (kt + 1 < nkt);
        RDA(cur, 0); RDB(cur, 0, b0);
        if (more) { STGA(nxt, kt + 1, 0); VMCNT(4); } else { VMCNT(2); }
        BARRIER;
        MM(b0, 0, 0);
        BARRIER;
        RDB(cur, 1, b1);
        if (more) { STGB(nxt, kt + 1, 0); VMCNT(4); } else { VMCNT(0); }
        BARRIER;
        MM(b1, 0, 2);
        BARRIER;
        RDA(cur, 1);
        if (more) STGB(nxt, kt + 1, 1);
        BARRIER;
        MM(b0, 4, 0);
        BARRIER;
        if (more) { STGA(nxt, kt + 1, 1); VMCNT(4); }
        BARRIER;
        MM(b1, 4, 2);
        BARRIER;
    }

    #pragma unroll
    for (int m = 0; m < 8; ++m)
        #pragma unroll
        for (int n = 0; n < 4; ++n)
            #pragma unroll
            for (int r = 0; r < 4; ++r) {
                size_t idx = (size_t)(brow + wm * 128 + m * 16 + lq * 4 + r) * N + bcol + wn * 64 + n * 16 + lr;
                if (OUTBF) ((u16*)Cout)[idx] = f2bf(acc[m][n][r]);
                else       ((float*)Cout)[idx] = acc[m][n][r];
            }
#undef STGA
#undef STGB
#undef RDA
#undef RDB
#undef MM
}

// ---------------- flash attention v13: diagonal-paired blocks, 4 waves, full-64kv/wave ----------------
// v12's dense decomposition + R9's in-block balance: block = q-tiles {ilo*64, (31-ilo)*64};
// wave w owns rows w*16..+15 of BOTH tiles (hi always active, lo for kt<=ilo — block-uniform).
// Steady phase = 68 MFMA/wave; block durations near-equal (17..32 phases, late ones hi-only)
// -> no per-CU drain (v12's 14.6% occupancy). lsum complete in-wave; direct store.
__global__ __launch_bounds__(256) void flash_attn(const u16* __restrict__ Q, const u16* __restrict__ K,
                                                  const u16* __restrict__ Vt, u16* __restrict__ Out) {
    __shared__ __align__(16) char smem[65536];   // K dbuf 2x16K | V dbuf 2x16K
    const int h = blockIdx.y;
    const int b = blockIdx.z;
    const int ilo = (b == 0) ? blockIdx.x : (15 - blockIdx.x);  // CU-pair complementary phase counts
    const int ihi = NQT - 1 - ilo;                // 16..31
    const int g = h >> 2;
    const int t = threadIdx.x;
    const int w = t >> 6, l = t & 63;
    const int lr = l & 15, lq = l >> 4;

    const size_t qhead = ((size_t)(b * NHq + h)) * Tt;
    bf16x8 qfl[4], qfh[4];
    #pragma unroll
    for (int d = 0; d < 4; ++d) {
        qfl[d] = *reinterpret_cast<const bf16x8*>(&Q[(qhead + ilo * 64 + w * 16 + lr) * HD + d * 32 + lq * 8]);
        qfh[d] = *reinterpret_cast<const bf16x8*>(&Q[(qhead + ihi * 64 + w * 16 + lr) * HD + d * 32 + lq * 8]);
    }
    bf16x8 ones;
    #pragma unroll
    for (int j = 0; j < 8; ++j) ones[j] = (__bf16)1.0f;

    f32x4 ol[8] = {}, oh[8] = {};
    f32x4 lsl = {}, lsh = {};

    const int qlo = ilo * 64 + w * 16 + lr;       // lane's q-row in lo / hi tile
    const int qhi = ihi * 64 + w * 16 + lr;
    const size_t kbase  = ((size_t)(b * NGk + g)) * Tt * HD;
    const size_t vtbase = ((size_t)(b * NGk + g)) * HD * Tt;
    const int nkt = ihi + 1;                      // 17..32 staged tiles

    int kofs[4], vofs[4];
    #pragma unroll
    for (int j = 0; j < 4; ++j) {
        int krow = j * 16 + (t >> 4);
        kofs[j] = krow * HD + (((t & 15) ^ (krow & 7)) * 8);
        int vrow = j * 32 + (t >> 3);
        vofs[j] = vrow * (int)Tt + (((t & 7) ^ (vrow & 7)) * 8);
    }

    // prologue: stage tile 0 into buf 0
    #pragma unroll
    for (int j = 0; j < 4; ++j) {
        GLOAD_LDS16(K + kbase + kofs[j], smem + (j * 256 + t) * 16);
        GLOAD_LDS16(Vt + vtbase + vofs[j], smem + 32768 + (j * 256 + t) * 16);
    }

    for (int kt = 0; kt < nkt; ++kt) {
        __syncthreads();                          // tile kt resident in buf kt&1 (drains vmcnt)
        if (kt + 1 < nkt) {
            const size_t kp1 = (size_t)(kt + 1) * 64;
            char* kd = smem + ((kt + 1) & 1) * 16384;
            char* vd = smem + 32768 + ((kt + 1) & 1) * 16384;
            #pragma unroll
            for (int j = 0; j < 4; ++j) {
                GLOAD_LDS16(K + kbase + kp1 * HD + kofs[j], kd + (j * 256 + t) * 16);
                GLOAD_LDS16(Vt + vtbase + kp1 + vofs[j], vd + (j * 256 + t) * 16);
            }
        }
        const char* Kb = smem + (kt & 1) * 16384;
        const char* Vb = smem + 32768 + (kt & 1) * 16384;
        const bool lo_act = (kt <= ilo);          // block-uniform

        // ---- S^T = K Q^T: 4 col-tiles of 16 kv; K-frags shared by lo/hi ----
        f32x4 sl[4] = {}, sh[4] = {};
        __builtin_amdgcn_s_setprio(1);
        #pragma unroll
        for (int ct = 0; ct < 4; ++ct) {
            #pragma unroll
            for (int d = 0; d < 4; ++d) {
                int row = ct * 16 + lr;
                int bo = row * 256 + ((d * 64 + lq * 16) ^ ((row & 7) << 4));
                bf16x8 kf = *reinterpret_cast<const bf16x8*>(Kb + bo);
                sh[ct] = __builtin_amdgcn_mfma_f32_16x16x32_bf16(kf, qfh[d], sh[ct], 0, 0, 0);
                if (lo_act) sl[ct] = __builtin_amdgcn_mfma_f32_16x16x32_bf16(kf, qfl[d], sl[ct], 0, 0, 0);
            }
        }
        __builtin_amdgcn_s_setprio(0);

        // ---- fixed-shift softmax in-register -> P fragments ----
        const int kvb = kt * 64 + lq * 4;
        bf16x8 pfh[2], pfl[2];
        {
            float e[4][4];
            #pragma unroll
            for (int ct = 0; ct < 4; ++ct)
                #pragma unroll
                for (int r = 0; r < 4; ++r)
                    e[ct][r] = exp2f(sh[ct][r]);
            if (kt == nkt - 1) {                  // hi diagonal tile
                #pragma unroll
                for (int ct = 0; ct < 4; ++ct)
                    #pragma unroll
                    for (int r = 0; r < 4; ++r)
                        if (kvb + ct * 16 + r > qhi) e[ct][r] = 0.f;
            }
            #pragma unroll
            for (int ks = 0; ks < 2; ++ks) {
                u32x4 pk;
                pk[0] = cvt_pk_bf16(e[ks * 2][0], e[ks * 2][1]);
                pk[1] = cvt_pk_bf16(e[ks * 2][2], e[ks * 2][3]);
                pk[2] = cvt_pk_bf16(e[ks * 2 + 1][0], e[ks * 2 + 1][1]);
                pk[3] = cvt_pk_bf16(e[ks * 2 + 1][2], e[ks * 2 + 1][3]);
                pfh[ks] = __builtin_bit_cast(bf16x8, pk);
            }
        }
        if (lo_act) {
            float e[4][4];
            #pragma unroll
            for (int ct = 0; ct < 4; ++ct)
                #pragma unroll
                for (int r = 0; r < 4; ++r)
                    e[ct][r] = exp2f(sl[ct][r]);
            if (kt == ilo) {                      // lo diagonal tile
                #pragma unroll
                for (int ct = 0; ct < 4; ++ct)
                    #pragma unroll
                    for (int r = 0; r < 4; ++r)
                        if (kvb + ct * 16 + r > qlo) e[ct][r] = 0.f;
            }
            #pragma unroll
            for (int ks = 0; ks < 2; ++ks) {
                u32x4 pk;
                pk[0] = cvt_pk_bf16(e[ks * 2][0], e[ks * 2][1]);
                pk[1] = cvt_pk_bf16(e[ks * 2][2], e[ks * 2][3]);
                pk[2] = cvt_pk_bf16(e[ks * 2 + 1][0], e[ks * 2 + 1][1]);
                pk[3] = cvt_pk_bf16(e[ks * 2 + 1][2], e[ks * 2 + 1][3]);
                pfl[ks] = __builtin_bit_cast(bf16x8, pk);
            }
        }

        // ---- O^T += V^T P ; l += ones . P  (V-frags shared by lo/hi) ----
        __builtin_amdgcn_s_setprio(1);
        #pragma unroll
        for (int n = 0; n < 8; ++n) {
            int vrow = n * 16 + lr;
            #pragma unroll
            for (int ks = 0; ks < 2; ++ks) {
                int bv = vrow * 128 + ((ks * 64 + lq * 16) ^ ((vrow & 7) << 4));
                bf16x8 vf = *reinterpret_cast<const bf16x8*>(Vb + bv);
                oh[n] = __builtin_amdgcn_mfma_f32_16x16x32_bf16(vf, pfh[ks], oh[n], 0, 0, 0);
                if (lo_act) ol[n] = __builtin_amdgcn_mfma_f32_16x16x32_bf16(vf, pfl[ks], ol[n], 0, 0, 0);
            }
        }
        lsh = __builtin_amdgcn_mfma_f32_16x16x32_bf16(ones, pfh[0], lsh, 0, 0, 0);
        lsh = __builtin_amdgcn_mfma_f32_16x16x32_bf16(ones, pfh[1], lsh, 0, 0, 0);
        if (lo_act) {
            lsl = __builtin_amdgcn_mfma_f32_16x16x32_bf16(ones, pfl[0], lsl, 0, 0, 0);
            lsl = __builtin_amdgcn_mfma_f32_16x16x32_bf16(ones, pfl[1], lsl, 0, 0, 0);
        }
        __builtin_amdgcn_s_setprio(0);
    }

    // ---- epilogue: normalize + store both tiles (lsum complete in-wave) ----
    {
        const float invh = 1.f / lsh[0];
        const float invl = 1.f / lsl[0];
        u16* outh = Out + ((size_t)(b * Tt) + qhi) * EMB + h * HD;
        u16* outl = Out + ((size_t)(b * Tt) + qlo) * EMB + h * HD;
        #pragma unroll
        for (int n = 0; n < 8; ++n) {
            uint2 ph, pl;
            ph.x = cvt_pk_bf16(oh[n][0] * invh, oh[n][1] * invh);
            ph.y = cvt_pk_bf16(oh[n][2] * invh, oh[n][3] * invh);
            pl.x = cvt_pk_bf16(ol[n][0] * invl, ol[n][1] * invl);
            pl.y = cvt_pk_bf16(ol[n][2] * invl, ol[n][3] * invl);
            *reinterpret_cast<uint2*>(&outh[n * 16 + lq * 4]) = ph;
            *reinterpret_cast<uint2*>(&outl[n * 16 + lq * 4]) = pl;
        }
    }
}

// ---------------- launcher ----------------
extern "C" void kernel_launch(void* const* d_in, const int* in_sizes, int n_in,
                              void* d_out, int out_size, void* d_ws, size_t ws_size,
                              hipStream_t stream) {
    (void)in_sizes; (void)n_in; (void)out_size; (void)ws_size;
    const float* x  = (const float*)d_in[0];
    const float* Wq = (const float*)d_in[1];
    const float* Wk = (const float*)d_in[2];
    const float* Wv = (const float*)d_in[3];
    const float* Wo = (const float*)d_in[4];
    float* out = (float*)d_out;

    char* ws = (char*)d_ws;
    size_t off = 0;
    auto alloc = [&](size_t bytes) { char* p = ws + off; off += (bytes + 255) & ~(size_t)255; return p; };

    u16* w_bf    = (u16*)alloc((size_t)(QKVN * EMB + EMB * EMB) * 2);  // Wq|Wk|Wv then Wo
    u16* x_bf    = (u16*)alloc((size_t)MROWS * EMB * 2);
    u16* qkv_lin = (u16*)alloc((size_t)MROWS * QKVN * 4);              // bf16 used; f32-size kept
    u16* Qb      = (u16*)alloc((size_t)Bb * NHq * Tt * HD * 2);
    u16* Kb      = (u16*)alloc((size_t)Bb * NGk * Tt * HD * 2);
    u16* Vtb     = (u16*)alloc((size_t)Bb * NGk * HD * Tt * 2);
    float* ctab  = (float*)alloc((size_t)Tt * 64 * 4);
    float* stab  = (float*)alloc((size_t)Tt * 64 * 4);
    u16* attnout = qkv_lin;         // alias: qkv_lin dead after rope/vtrans

    u16* wo_bf = w_bf + (size_t)QKVN * EMB;

    // 1. casts (x + fused weights) + tables
    cast_bf16_kernel<<<(MROWS * EMB / 4 + 255) / 256, 256, 0, stream>>>(x, x_bf, MROWS * EMB / 4);
    wcast_kernel<<<(QKVN * EMB + EMB * EMB) / 4 / 256, 256, 0, stream>>>(Wq, Wk, Wv, Wo, w_bf);
    rope_tables_kernel<<<Tt, 64, 0, stream>>>(ctab, stab);

    // 2. fused QKV projection (256^2 4-phase v2): qkv_lin bf16 = x_bf @ [Wq;Wk;Wv]^T
    gemm256<1><<<dim3((MROWS / 256) * (QKVN / 256)), 512, 0, stream>>>(x_bf, w_bf, qkv_lin, MROWS, QKVN, EMB);

    // 3. RoPE q+k (fused) + V transpose (+ fold softmax scale*log2e into Q)
    const float qscale = 1.44269504088896f / sqrtf((float)HD);
    rope_qk_kernel<<<dim3(Tt / 4, NHq + NGk, Bb), dim3(64, 4), 0, stream>>>(qkv_lin, ctab, stab, Qb, Kb, qscale);
    vtrans_kernel<<<dim3(Tt / 64, NGk, Bb), dim3(64, 8), 0, stream>>>(qkv_lin, Vtb);

    // 4. flash attention (diagonal-paired 4-wave dense) -> attnout bf16 [B][T][EMB]
    flash_attn<<<dim3(16, NHq, Bb), 256, 0, stream>>>(Qb, Kb, Vtb, attnout);

    // 5. output projection: 128^2 m97 structure (256 wgs -> full machine at 2 blocks/CU)
    gemm_bt<0><<<dim3(MROWS / 128, EMB / 128), 256, 0, stream>>>(attnout, wo_bf, out, MROWS, EMB, EMB);
}

// Round 16
// 221.351 us; speedup vs baseline: 1.0545x; 1.0545x over previous
//
#include <hip/hip_runtime.h>
#include <stdint.h>
#include <math.h>

#define EMB 2048
#define NHq 16
#define NGk 4
#define HD 128
#define Bb 2
#define Tt 2048
#define MROWS (Bb*Tt)      // 4096
#define QKVN 3072          // 2048 q + 512 k + 512 v
#define NQT 32             // q-tiles of 64 rows per (b,h)

typedef __bf16 bf16x8 __attribute__((ext_vector_type(8)));
typedef float f32x4 __attribute__((ext_vector_type(4)));
typedef unsigned int u32x4 __attribute__((ext_vector_type(4)));
typedef unsigned short u16;
typedef unsigned int u32;

__device__ __forceinline__ u16 f2bf(float f) {
    unsigned int u = __float_as_uint(f);
    u += 0x7fff + ((u >> 16) & 1);          // round-to-nearest-even
    return (u16)(u >> 16);
}
__device__ __forceinline__ float bf2f(u16 u) {
    return __uint_as_float(((u32)u) << 16);
}
__device__ __forceinline__ u32 cvt_pk_bf16(float lo, float hi) {
    u32 r;
    asm("v_cvt_pk_bf16_f32 %0, %1, %2" : "=v"(r) : "v"(lo), "v"(hi));
    return r;
}

#define GLOAD_LDS16(g, l) \
    __builtin_amdgcn_global_load_lds((const __attribute__((address_space(1))) void*)(g), \
                                     (__attribute__((address_space(3))) void*)(l), 16, 0, 0)
#define FENCE asm volatile("" ::: "memory")
#define BARRIER { FENCE; __builtin_amdgcn_s_barrier(); FENCE; }
#define VMCNT(n) asm volatile("s_waitcnt vmcnt(" #n ")")

// ---------------- cast f32 -> bf16, vectorized ----------------
__global__ void cast_bf16_kernel(const float* __restrict__ src, u16* __restrict__ dst, int n4) {
    int i = blockIdx.x * blockDim.x + threadIdx.x;
    if (i < n4) {
        float4 v = reinterpret_cast<const float4*>(src)[i];
        ushort4 o;
        o.x = f2bf(v.x); o.y = f2bf(v.y); o.z = f2bf(v.z); o.w = f2bf(v.w);
        reinterpret_cast<ushort4*>(dst)[i] = o;
    }
}

// ---------------- fused weight cast: Wq|Wk|Wv|Wo -> contiguous bf16 ----------------
__global__ void wcast_kernel(const float* __restrict__ Wq, const float* __restrict__ Wk,
                             const float* __restrict__ Wv, const float* __restrict__ Wo,
                             u16* __restrict__ dst) {
    int i = blockIdx.x * blockDim.x + threadIdx.x;     // float4 chunk index, 2621440 total
    const float* src; int local;
    if (i < 1048576)      { src = Wq; local = i; }
    else if (i < 1310720) { src = Wk; local = i - 1048576; }
    else if (i < 1572864) { src = Wv; local = i - 1310720; }
    else                  { src = Wo; local = i - 1572864; }
    float4 v = reinterpret_cast<const float4*>(src)[local];
    ushort4 o;
    o.x = f2bf(v.x); o.y = f2bf(v.y); o.z = f2bf(v.z); o.w = f2bf(v.w);
    reinterpret_cast<ushort4*>(dst)[i] = o;
}

// ---------------- RoPE cos/sin tables: [T][64] ----------------
__global__ void rope_tables_kernel(float* __restrict__ ctab, float* __restrict__ stab) {
    int t = blockIdx.x, i = threadIdx.x;     // grid T, block 64
    float inv = powf(10000.f, -2.f * (float)i / (float)HD);
    float ang = (float)t * inv;
    ctab[t * 64 + i] = cosf(ang);
    stab[t * 64 + i] = sinf(ang);
}

// ---------------- fused RoPE q+k: lin[M][3072] bf16 -> Qb / Kb bf16 ----------------
__global__ void rope_qk_kernel(const u16* __restrict__ lin, const float* __restrict__ ctab,
                               const float* __restrict__ stab, u16* __restrict__ Qb,
                               u16* __restrict__ Kb, float qscale) {
    // grid (T/4, NHq+NGk, B), block (64,4)
    int i = threadIdx.x;                       // pair index 0..63
    int tt = blockIdx.x * 4 + threadIdx.y;
    int hh = blockIdx.y, b = blockIdx.z;
    int coloff; u16* out; float scale;
    if (hh < NHq) { coloff = hh * HD; scale = qscale;
                    out = Qb + (((size_t)(b * NHq + hh)) * Tt + tt) * HD; }
    else { int g = hh - NHq; coloff = EMB + g * HD; scale = 1.f;
           out = Kb + (((size_t)(b * NGk + g)) * Tt + tt) * HD; }
    u32 pair = *reinterpret_cast<const u32*>(&lin[((size_t)(b * Tt + tt)) * QKVN + coloff + 2 * i]);
    float x1 = bf2f((u16)(pair & 0xffff)), x2 = bf2f((u16)(pair >> 16));
    float c = ctab[tt * 64 + i], s = stab[tt * 64 + i];
    ushort2 o;
    o.x = f2bf((x1 * c - x2 * s) * scale);
    o.y = f2bf((x1 * s + x2 * c) * scale);
    *reinterpret_cast<ushort2*>(&out[2 * i]) = o;
}

// ---------------- V relayout+transpose (bf16 copy): lin -> Vt[B][NG][HD][T], kv sigma-PERMUTED ----
__global__ void vtrans_kernel(const u16* __restrict__ lin, u16* __restrict__ vt) {
    // grid (T/64, NG, B), block (64,8)
    int tx = threadIdx.x, dy = threadIdx.y;
    int tt = blockIdx.x * 64 + tx;
    int g = blockIdx.y, b = blockIdx.z;
    int ttp = (tt & ~31) | (((tt >> 2) & 3) * 8 + ((tt >> 4) & 1) * 4 + (tt & 3));
    const u16* src = &lin[((size_t)(b * Tt + tt)) * QKVN + EMB + NGk * HD + g * HD];
    u16* dst = &vt[(((size_t)(b * NGk + g)) * HD) * Tt + ttp];
    #pragma unroll
    for (int k = 0; k < 16; ++k) {
        int d = dy + k * 8;
        dst[(size_t)d * Tt] = src[d];
    }
}

// ---------------- bf16 GEMM 128^2 (m97 structure): C = A @ W^T ----------------
template<int OUTBF>
__global__ __launch_bounds__(256) void gemm_bt(const u16* __restrict__ A, const u16* __restrict__ W,
                                               void* __restrict__ Cout, int M, int N, int K) {
    __shared__ u16 Atile[128 * 32];
    __shared__ u16 Btile[128 * 32];
    const int brow = blockIdx.x * 128;
    const int bcol = blockIdx.y * 128;
    const int t = threadIdx.x;
    const int w = t >> 6, l = t & 63;
    const int lr = l & 15, lq = l >> 4;
    const int wr = (w >> 1) * 64, wc = (w & 1) * 64;
    f32x4 acc[4][4] = {};
    const int nkt = K >> 5;
    for (int kt = 0; kt < nkt; ++kt) {
        const int k0 = kt * 32;
        #pragma unroll
        for (int i = 0; i < 2; ++i) {
            int f = i * 256 + t;
            int row = f >> 2, cb = (f & 3) * 8;
            GLOAD_LDS16(A + (size_t)(brow + row) * K + k0 + cb, &Atile[(i * 256 + w * 64) * 8]);
            GLOAD_LDS16(W + (size_t)(bcol + row) * K + k0 + cb, &Btile[(i * 256 + w * 64) * 8]);
        }
        __syncthreads();
        bf16x8 a[4], b[4];
        #pragma unroll
        for (int m = 0; m < 4; ++m)
            a[m] = *reinterpret_cast<const bf16x8*>(&Atile[(wr + m * 16 + lr) * 32 + lq * 8]);
        #pragma unroll
        for (int n = 0; n < 4; ++n)
            b[n] = *reinterpret_cast<const bf16x8*>(&Btile[(wc + n * 16 + lr) * 32 + lq * 8]);
        #pragma unroll
        for (int m = 0; m < 4; ++m)
            #pragma unroll
            for (int n = 0; n < 4; ++n)
                acc[m][n] = __builtin_amdgcn_mfma_f32_16x16x32_bf16(a[m], b[n], acc[m][n], 0, 0, 0);
        __syncthreads();
    }
    #pragma unroll
    for (int m = 0; m < 4; ++m)
        #pragma unroll
        for (int n = 0; n < 4; ++n)
            #pragma unroll
            for (int r = 0; r < 4; ++r) {
                size_t idx = (size_t)(brow + wr + m * 16 + lq * 4 + r) * N + bcol + wc + n * 16 + lr;
                if (OUTBF) ((u16*)Cout)[idx] = f2bf(acc[m][n][r]);
                else       ((float*)Cout)[idx] = acc[m][n][r];
            }
}

// ---------------- 256x256 4-phase GEMM v2: quadrant-aligned halftiles, reg-held B ----------------
template<int OUTBF>
__global__ __launch_bounds__(512) void gemm256(const u16* __restrict__ A, const u16* __restrict__ W,
                                               void* __restrict__ Cout, int M, int N, int K) {
    __shared__ __align__(16) char smem[131072];   // buf d: A 32KB @ d*65536, B 32KB @ +32768
    const int nbm = M >> 8;
    const int nwg = gridDim.x;
    const int cpx = nwg >> 3;
    const int swz = ((int)blockIdx.x & 7) * cpx + ((int)blockIdx.x >> 3);
    const int brow = (swz % nbm) << 8;
    const int bcol = (swz / nbm) << 8;
    const int t = threadIdx.x;
    const int l = t & 63, lr = l & 15, lq = l >> 4;
    const int w = t >> 6, wm = w >> 2, wn = w & 3;

    int lrj[2], slj[2], sej[2];
    #pragma unroll
    for (int j = 0; j < 2; ++j) {
        int c = j * 512 + t;
        lrj[j] = c >> 3; slj[j] = c & 7; sej[j] = (c & 7) ^ ((c >> 3) & 7);
    }

#define STGA(d, kt1, h) { \
    _Pragma("unroll") \
    for (int j = 0; j < 2; ++j) { \
        int row = (lrj[j] & 63) + (h) * 64 + (lrj[j] >> 6) * 128; \
        GLOAD_LDS16(A + (size_t)(brow + row) * K + (size_t)(kt1) * 64 + sej[j] * 8, \
                    smem + (d) * 65536 + row * 128 + slj[j] * 16); } }
#define STGB(d, kt1, h) { \
    _Pragma("unroll") \
    for (int j = 0; j < 2; ++j) { \
        int row = (lrj[j] & 31) + (h) * 32 + (lrj[j] >> 5) * 64; \
        GLOAD_LDS16(W + (size_t)(bcol + row) * K + (size_t)(kt1) * 64 + sej[j] * 8, \
                    smem + (d) * 65536 + 32768 + row * 128 + slj[j] * 16); } }
#define RDA(cur, mh) { \
    _Pragma("unroll") \
    for (int m = 0; m < 4; ++m) \
        _Pragma("unroll") \
        for (int kk = 0; kk < 2; ++kk) { \
            int row = wm * 128 + (mh) * 64 + m * 16 + lr; \
            int slr = (kk * 4 + lq) ^ (lr & 7); \
            af[m][kk] = *reinterpret_cast<const bf16x8*>(smem + (cur) * 65536 + row * 128 + slr * 16); } }
#define RDB(cur, nh, bq) { \
    _Pragma("unroll") \
    for (int n = 0; n < 2; ++n) \
        _Pragma("unroll") \
        for (int kk = 0; kk < 2; ++kk) { \
            int row = wn * 64 + (nh) * 32 + n * 16 + lr; \
            int slr = (kk * 4 + lq) ^ (lr & 7); \
            bq[n][kk] = *reinterpret_cast<const bf16x8*>(smem + (cur) * 65536 + 32768 + row * 128 + slr * 16); } }
#define MM(bq, mo, no) { \
    __builtin_amdgcn_s_setprio(1); \
    _Pragma("unroll") \
    for (int m = 0; m < 4; ++m) \
        _Pragma("unroll") \
        for (int n = 0; n < 2; ++n) \
            _Pragma("unroll") \
            for (int kk = 0; kk < 2; ++kk) \
                acc[(mo) + m][(no) + n] = __builtin_amdgcn_mfma_f32_16x16x32_bf16( \
                    af[m][kk], bq[n][kk], acc[(mo) + m][(no) + n], 0, 0, 0); \
    __builtin_amdgcn_s_setprio(0); }

    f32x4 acc[8][4] = {};
    bf16x8 af[4][2], b0[2][2], b1[2][2];
    const int nkt = K >> 6;

    STGA(0, 0, 0); STGB(0, 0, 0); STGB(0, 0, 1); STGA(0, 0, 1);
    VMCNT(4); BARRIER;

    for (int kt = 0; kt < nkt; ++kt) {
        const int cur = kt & 1, nxt = cur ^ 1;
        const bool more = (kt + 1 < nkt);
        RDA(cur, 0); RDB(cur, 0, b0);
        if (more) { STGA(nxt, kt + 1, 0); VMCNT(4); } else { VMCNT(2); }
        BARRIER;
        MM(b0, 0, 0);
        BARRIER;
        RDB(cur, 1, b1);
        if (more) { STGB(nxt, kt + 1, 0); VMCNT(4); } else { VMCNT(0); }
        BARRIER;
        MM(b1, 0, 2);
        BARRIER;
        RDA(cur, 1);
        if (more) STGB(nxt, kt + 1, 1);
        BARRIER;
        MM(b0, 4, 0);
        BARRIER;
        if (more) { STGA(nxt, kt + 1, 1); VMCNT(4); }
        BARRIER;
        MM(b1, 4, 2);
        BARRIER;
    }

    #pragma unroll
    for (int m = 0; m < 8; ++m)
        #pragma unroll
        for (int n = 0; n < 4; ++n)
            #pragma unroll
            for (int r = 0; r < 4; ++r) {
                size_t idx = (size_t)(brow + wm * 128 + m * 16 + lq * 4 + r) * N + bcol + wn * 64 + n * 16 + lr;
                if (OUTBF) ((u16*)Cout)[idx] = f2bf(acc[m][n][r]);
                else       ((float*)Cout)[idx] = acc[m][n][r];
            }
#undef STGA
#undef STGB
#undef RDA
#undef RDB
#undef MM
}

// ---------------- flash attention v12 (best measured: 84.5us): 4 waves x 32 q-rows, full-64kv ----------------
__global__ __launch_bounds__(256) void flash_attn(const u16* __restrict__ Q, const u16* __restrict__ K,
                                                  const u16* __restrict__ Vt, u16* __restrict__ Out) {
    __shared__ __align__(16) char smem[65536];   // K dbuf 2x16K | V dbuf 2x16K
    const int h = blockIdx.y;
    const int b = blockIdx.z;
    const int qt = (b == 0) ? blockIdx.x : (15 - blockIdx.x);   // q-tile of 128 rows
    const int g = h >> 2;
    const int t = threadIdx.x;
    const int w = t >> 6, l = t & 63;
    const int lr = l & 15, lq = l >> 4;
    const int qbase = qt * 128 + w * 32;          // wave's first q-row

    const size_t qhead = ((size_t)(b * NHq + h)) * Tt;
    bf16x8 qf0[4], qf1[4];
    #pragma unroll
    for (int d = 0; d < 4; ++d) {
        qf0[d] = *reinterpret_cast<const bf16x8*>(&Q[(qhead + qbase + lr) * HD + d * 32 + lq * 8]);
        qf1[d] = *reinterpret_cast<const bf16x8*>(&Q[(qhead + qbase + 16 + lr) * HD + d * 32 + lq * 8]);
    }
    bf16x8 ones;
    #pragma unroll
    for (int j = 0; j < 8; ++j) ones[j] = (__bf16)1.0f;

    f32x4 o0[8] = {}, o1[8] = {};
    f32x4 ls0 = {}, ls1 = {};

    const int q0 = qbase + lr;
    const int q1 = qbase + 16 + lr;
    const int lastvis = (qbase + 31) >> 6;
    const size_t kbase  = ((size_t)(b * NGk + g)) * Tt * HD;
    const size_t vtbase = ((size_t)(b * NGk + g)) * HD * Tt;
    const int nkt = 2 * (qt + 1);

    int kofs[4], vofs[4];
    #pragma unroll
    for (int j = 0; j < 4; ++j) {
        int krow = j * 16 + (t >> 4);
        kofs[j] = krow * HD + (((t & 15) ^ (krow & 7)) * 8);
        int vrow = j * 32 + (t >> 3);
        vofs[j] = vrow * (int)Tt + (((t & 7) ^ (vrow & 7)) * 8);
    }

    #pragma unroll
    for (int j = 0; j < 4; ++j) {
        GLOAD_LDS16(K + kbase + kofs[j], smem + (j * 256 + t) * 16);
        GLOAD_LDS16(Vt + vtbase + vofs[j], smem + 32768 + (j * 256 + t) * 16);
    }

    for (int kt = 0; kt < nkt; ++kt) {
        __syncthreads();
        if (kt + 1 < nkt) {
            const size_t kp1 = (size_t)(kt + 1) * 64;
            char* kd = smem + ((kt + 1) & 1) * 16384;
            char* vd = smem + 32768 + ((kt + 1) & 1) * 16384;
            #pragma unroll
            for (int j = 0; j < 4; ++j) {
                GLOAD_LDS16(K + kbase + kp1 * HD + kofs[j], kd + (j * 256 + t) * 16);
                GLOAD_LDS16(Vt + vtbase + kp1 + vofs[j], vd + (j * 256 + t) * 16);
            }
        }
        if (kt > lastvis) continue;
        const char* Kb = smem + (kt & 1) * 16384;
        const char* Vb = smem + 32768 + (kt & 1) * 16384;

        f32x4 s0[4] = {}, s1[4] = {};
        __builtin_amdgcn_s_setprio(1);
        #pragma unroll
        for (int ct = 0; ct < 4; ++ct) {
            #pragma unroll
            for (int d = 0; d < 4; ++d) {
                int row = ct * 16 + lr;
                int bo = row * 256 + ((d * 64 + lq * 16) ^ ((row & 7) << 4));
                bf16x8 kf = *reinterpret_cast<const bf16x8*>(Kb + bo);
                s0[ct] = __builtin_amdgcn_mfma_f32_16x16x32_bf16(kf, qf0[d], s0[ct], 0, 0, 0);
                s1[ct] = __builtin_amdgcn_mfma_f32_16x16x32_bf16(kf, qf1[d], s1[ct], 0, 0, 0);
            }
        }
        __builtin_amdgcn_s_setprio(0);

        const bool diag = (kt == lastvis);
        const int kvb = kt * 64 + lq * 4;
        bf16x8 pf0[2], pf1[2];
        {
            float e[4][4];
            #pragma unroll
            for (int ct = 0; ct < 4; ++ct)
                #pragma unroll
                for (int r = 0; r < 4; ++r)
                    e[ct][r] = exp2f(s0[ct][r]);
            if (diag) {
                #pragma unroll
                for (int ct = 0; ct < 4; ++ct)
                    #pragma unroll
                    for (int r = 0; r < 4; ++r)
                        if (kvb + ct * 16 + r > q0) e[ct][r] = 0.f;
            }
            #pragma unroll
            for (int ks = 0; ks < 2; ++ks) {
                u32x4 pk;
                pk[0] = cvt_pk_bf16(e[ks * 2][0], e[ks * 2][1]);
                pk[1] = cvt_pk_bf16(e[ks * 2][2], e[ks * 2][3]);
                pk[2] = cvt_pk_bf16(e[ks * 2 + 1][0], e[ks * 2 + 1][1]);
                pk[3] = cvt_pk_bf16(e[ks * 2 + 1][2], e[ks * 2 + 1][3]);
                pf0[ks] = __builtin_bit_cast(bf16x8, pk);
            }
        }
        {
            float e[4][4];
            #pragma unroll
            for (int ct = 0; ct < 4; ++ct)
                #pragma unroll
                for (int r = 0; r < 4; ++r)
                    e[ct][r] = exp2f(s1[ct][r]);
            if (diag) {
                #pragma unroll
                for (int ct = 0; ct < 4; ++ct)
                    #pragma unroll
                    for (int r = 0; r < 4; ++r)
                        if (kvb + ct * 16 + r > q1) e[ct][r] = 0.f;
            }
            #pragma unroll
            for (int ks = 0; ks < 2; ++ks) {
                u32x4 pk;
                pk[0] = cvt_pk_bf16(e[ks * 2][0], e[ks * 2][1]);
                pk[1] = cvt_pk_bf16(e[ks * 2][2], e[ks * 2][3]);
                pk[2] = cvt_pk_bf16(e[ks * 2 + 1][0], e[ks * 2 + 1][1]);
                pk[3] = cvt_pk_bf16(e[ks * 2 + 1][2], e[ks * 2 + 1][3]);
                pf1[ks] = __builtin_bit_cast(bf16x8, pk);
            }
        }

        __builtin_amdgcn_s_setprio(1);
        #pragma unroll
        for (int n = 0; n < 8; ++n) {
            int vrow = n * 16 + lr;
            #pragma unroll
            for (int ks = 0; ks < 2; ++ks) {
                int bv = vrow * 128 + ((ks * 64 + lq * 16) ^ ((vrow & 7) << 4));
                bf16x8 vf = *reinterpret_cast<const bf16x8*>(Vb + bv);
                o0[n] = __builtin_amdgcn_mfma_f32_16x16x32_bf16(vf, pf0[ks], o0[n], 0, 0, 0);
                o1[n] = __builtin_amdgcn_mfma_f32_16x16x32_bf16(vf, pf1[ks], o1[n], 0, 0, 0);
            }
        }
        ls0 = __builtin_amdgcn_mfma_f32_16x16x32_bf16(ones, pf0[0], ls0, 0, 0, 0);
        ls0 = __builtin_amdgcn_mfma_f32_16x16x32_bf16(ones, pf0[1], ls0, 0, 0, 0);
        ls1 = __builtin_amdgcn_mfma_f32_16x16x32_bf16(ones, pf1[0], ls1, 0, 0, 0);
        ls1 = __builtin_amdgcn_mfma_f32_16x16x32_bf16(ones, pf1[1], ls1, 0, 0, 0);
        __builtin_amdgcn_s_setprio(0);
    }

    {
        const float inv0 = 1.f / ls0[0];
        const float inv1 = 1.f / ls1[0];
        u16* out0 = Out + ((size_t)(b * Tt) + q0) * EMB + h * HD;
        u16* out1 = Out + ((size_t)(b * Tt) + q1) * EMB + h * HD;
        #pragma unroll
        for (int n = 0; n < 8; ++n) {
            uint2 p0, p1;
            p0.x = cvt_pk_bf16(o0[n][0] * inv0, o0[n][1] * inv0);
            p0.y = cvt_pk_bf16(o0[n][2] * inv0, o0[n][3] * inv0);
            p1.x = cvt_pk_bf16(o1[n][0] * inv1, o1[n][1] * inv1);
            p1.y = cvt_pk_bf16(o1[n][2] * inv1, o1[n][3] * inv1);
            *reinterpret_cast<uint2*>(&out0[n * 16 + lq * 4]) = p0;
            *reinterpret_cast<uint2*>(&out1[n * 16 + lq * 4]) = p1;
        }
    }
}

// ---------------- launcher ----------------
extern "C" void kernel_launch(void* const* d_in, const int* in_sizes, int n_in,
                              void* d_out, int out_size, void* d_ws, size_t ws_size,
                              hipStream_t stream) {
    (void)in_sizes; (void)n_in; (void)out_size; (void)ws_size;
    const float* x  = (const float*)d_in[0];
    const float* Wq = (const float*)d_in[1];
    const float* Wk = (const float*)d_in[2];
    const float* Wv = (const float*)d_in[3];
    const float* Wo = (const float*)d_in[4];
    float* out = (float*)d_out;

    char* ws = (char*)d_ws;
    size_t off = 0;
    auto alloc = [&](size_t bytes) { char* p = ws + off; off += (bytes + 255) & ~(size_t)255; return p; };

    u16* w_bf    = (u16*)alloc((size_t)(QKVN * EMB + EMB * EMB) * 2);  // Wq|Wk|Wv then Wo
    u16* x_bf    = (u16*)alloc((size_t)MROWS * EMB * 2);
    u16* qkv_lin = (u16*)alloc((size_t)MROWS * QKVN * 4);              // bf16 used; f32-size kept
    u16* Qb      = (u16*)alloc((size_t)Bb * NHq * Tt * HD * 2);
    u16* Kb      = (u16*)alloc((size_t)Bb * NGk * Tt * HD * 2);
    u16* Vtb     = (u16*)alloc((size_t)Bb * NGk * HD * Tt * 2);
    float* ctab  = (float*)alloc((size_t)Tt * 64 * 4);
    float* stab  = (float*)alloc((size_t)Tt * 64 * 4);
    u16* attnout = qkv_lin;         // alias: qkv_lin dead after rope/vtrans

    u16* wo_bf = w_bf + (size_t)QKVN * EMB;

    // 1. casts (x + fused weights) + tables
    cast_bf16_kernel<<<(MROWS * EMB / 4 + 255) / 256, 256, 0, stream>>>(x, x_bf, MROWS * EMB / 4);
    wcast_kernel<<<(QKVN * EMB + EMB * EMB) / 4 / 256, 256, 0, stream>>>(Wq, Wk, Wv, Wo, w_bf);
    rope_tables_kernel<<<Tt, 64, 0, stream>>>(ctab, stab);

    // 2. fused QKV projection (256^2 4-phase v2): qkv_lin bf16 = x_bf @ [Wq;Wk;Wv]^T
    gemm256<1><<<dim3((MROWS / 256) * (QKVN / 256)), 512, 0, stream>>>(x_bf, w_bf, qkv_lin, MROWS, QKVN, EMB);

    // 3. RoPE q+k (fused) + V transpose (+ fold softmax scale*log2e into Q)
    const float qscale = 1.44269504088896f / sqrtf((float)HD);
    rope_qk_kernel<<<dim3(Tt / 4, NHq + NGk, Bb), dim3(64, 4), 0, stream>>>(qkv_lin, ctab, stab, Qb, Kb, qscale);
    vtrans_kernel<<<dim3(Tt / 64, NGk, Bb), dim3(64, 8), 0, stream>>>(qkv_lin, Vtb);

    // 4. flash attention (4-wave dense decomposition, v12) -> attnout bf16 [B][T][EMB]
    flash_attn<<<dim3(16, NHq, Bb), 256, 0, stream>>>(Qb, Kb, Vtb, attnout);

    // 5. output projection: 128^2 m97 structure (256 wgs -> full machine at 2 blocks/CU)
    gemm_bt<0><<<dim3(MROWS / 128, EMB / 128), 256, 0, stream>>>(attnout, wo_bf, out, MROWS, EMB, EMB);
}